// Round 2
// baseline (491.053 us; speedup 1.0000x reference)
//
#include <hip/hip_runtime.h>
#include <hip/hip_bf16.h>

#define M_LEN 1024
#define BATCH 16384

#define BM 128
#define BN 128
#define BK 64
#define THREADS 256

typedef __attribute__((ext_vector_type(8))) short bf16x8;
typedef __attribute__((ext_vector_type(4))) float f32x4;
typedef unsigned short ushort_t;

// ---------------- helpers ----------------

// fp32 -> bf16 RNE
__device__ __forceinline__ ushort_t bf16_rne(float f) {
    unsigned u = __float_as_uint(f);
    unsigned r = u + 0x7FFFu + ((u >> 16) & 1u);
    return (ushort_t)(r >> 16);
}

// pack two fp32 -> two bf16 (RTZ) in one v_perm_b32 (fallback kernel only)
__device__ __forceinline__ unsigned pack2(float lo, float hi) {
    return __builtin_amdgcn_perm(__float_as_uint(hi), __float_as_uint(lo), 0x07060302u);
}

// async global->LDS, 16B per lane. LDS dest is wave-uniform base + lane*16.
__device__ __forceinline__ void gload_lds16(const void* g, void* l) {
    __builtin_amdgcn_global_load_lds(
        (const __attribute__((address_space(1))) unsigned int*)g,
        (__attribute__((address_space(3))) unsigned int*)l,
        16, 0, 0);
}

// ---------------- prologue: W fp32 -> bf16 (4 MB read, 2 MB write, ~3 us) -------
__global__ __launch_bounds__(THREADS) void convert_w(
    const float* __restrict__ W, ushort_t* __restrict__ Wb)
{
    const int wave = threadIdx.x >> 6;
    const int lane = threadIdx.x & 63;
    const int r = blockIdx.x * 4 + wave;          // grid = 256 -> rows 0..1023
    const float4* row = (const float4*)(W + (size_t)r * M_LEN);
    ushort_t* dst = Wb + (size_t)r * M_LEN;
    #pragma unroll
    for (int j = 0; j < 4; ++j) {
        float4 v = row[j * 64 + lane];
        ushort4 o;
        o.x = bf16_rne(v.x); o.y = bf16_rne(v.y);
        o.z = bf16_rne(v.z); o.w = bf16_rne(v.w);
        ((ushort4*)dst)[j * 64 + lane] = o;
    }
}

// ---------------- main: fused fp32-A GEMM + softmax epilogue ----------------
// Round-2 structure (post-mortem of rounds 0/1):
//  - single-buffered LDS, plain __syncthreads 2-barrier loop (round-1 lesson:
//    hand-rolled dbuf+asm-waitcnt regressed 191->223; 33 KB LDS keeps 4 blk/CU
//    whose implicit cross-block overlap is the real latency hiding, m114)
//  - T1 XCD swizzle kept (round-1 confirmed: FETCH 585->138 MB)
//  - A read directly as fp32 from mods, converted RNE in-kernel -> deletes the
//    ~200 us convert_pass and its 130 MB workspace round-trip entirely
//  - B staged async (gload_lds16) from 2 MB bf16 Wb, pre-swizzled source
//  - zero-row flags via in-kernel OR accumulation (signs stripped)
//  - epilogue x read as fp32 (L2-hot panel) -> numerics >= round-0 version
__global__ __launch_bounds__(THREADS) void gemm_fused2(
    const float* __restrict__ mod0, const float* __restrict__ mod1,
    const float* __restrict__ mod2, const float* __restrict__ mod3,
    const ushort_t* __restrict__ Wb, float* __restrict__ out)
{
    __shared__ __align__(16) ushort_t As[BM * BK];   // 16 KB
    __shared__ __align__(16) ushort_t Bs[BN * BK];   // 16 KB
    __shared__ unsigned rowOr[BM];
    __shared__ float scalerS[BM / 4];

    const int t    = threadIdx.x;
    const int lane = t & 63;
    const int wave = t >> 6;
    const int quad = lane >> 4;
    const int ln15 = lane & 15;
    const int wm   = wave >> 1;
    const int wn   = wave & 1;

    // T1: XCD-aware remap. 4096 blocks, 8 XCDs, 4096 % 8 == 0 -> bijective.
    const int bid  = blockIdx.x;
    const int wid  = (bid & 7) * 512 + (bid >> 3);
    const int colb = wid & 7;
    const int rowb = wid >> 3;
    const int row0 = rowb * BM;
    const int col0 = colb * BN;

    if (t < BM) rowOr[t] = 0u;

    // ---- A staging setup (fp32 -> bf16, ds_write with XOR swizzle) ----
    const int sr  = t >> 3;      // 0..31  (row within 32-row group)
    const int scl = t & 7;       // 0..7   (global 16B chunk index)
    const float* ap[4];
    unsigned ldsOffA[4];
    unsigned orAcc[4] = {0u, 0u, 0u, 0u};
    #pragma unroll
    for (int j = 0; j < 4; ++j) {
        const int r  = j * 32 + sr;
        const int gr = row0 + r;
        const int b  = gr >> 2;
        const int m  = gr & 3;
        const float* mp = (m == 0) ? mod0 : (m == 1) ? mod1 : (m == 2) ? mod2 : mod3;
        ap[j] = mp + (size_t)b * M_LEN + scl * 8;
        ldsOffA[j] = (unsigned)(r * 64 + ((scl ^ (r & 7)) * 8));   // ushort units
    }

    // ---- B staging setup (bf16 async, swizzle applied on global source) ----
    const int rloc = (lane >> 3);
    const int cB   = (lane & 7) ^ rloc;
    const ushort_t* bPtr[4];
    #pragma unroll
    for (int q = 0; q < 4; ++q) {
        const int r = wave * 32 + q * 8 + rloc;
        bPtr[q] = Wb + (size_t)(col0 + r) * M_LEN + cB * 8;
    }

    f32x4 acc[4][4];
    #pragma unroll
    for (int i = 0; i < 4; ++i)
        #pragma unroll
        for (int j = 0; j < 4; ++j)
            acc[i][j] = (f32x4){0.f, 0.f, 0.f, 0.f};

    const unsigned slotB   = (unsigned)(quad ^ (ln15 & 7));
    const unsigned aRowOff = (unsigned)((wm * 64 + ln15) * 64);
    const unsigned bRowOff = (unsigned)((wn * 64 + ln15) * 64);

    for (int it = 0; it < 16; ++it) {
        __syncthreads();   // prev-tile LDS reads done (compiler drains counts)

        // B: async global->LDS, zero VALU
        #pragma unroll
        for (int q = 0; q < 4; ++q) {
            gload_lds16(bPtr[q], &Bs[(wave * 4 + q) * 512]);
            bPtr[q] += BK;
        }

        // A: issue all fp32 loads first (8 in flight), then convert+write
        float4 a0[4], a1[4];
        #pragma unroll
        for (int j = 0; j < 4; ++j) {
            const float4* pa = (const float4*)ap[j];
            a0[j] = pa[0];
            a1[j] = pa[1];
            ap[j] += BK;
        }
        #pragma unroll
        for (int j = 0; j < 4; ++j) {
            const unsigned w0 = __float_as_uint(a0[j].x) | __float_as_uint(a0[j].y) |
                                __float_as_uint(a0[j].z) | __float_as_uint(a0[j].w);
            const unsigned w1 = __float_as_uint(a1[j].x) | __float_as_uint(a1[j].y) |
                                __float_as_uint(a1[j].z) | __float_as_uint(a1[j].w);
            orAcc[j] |= (w0 | w1) << 1;   // drop sign bits; bits30..0 preserved
            ushort4 lo, hi;
            lo.x = bf16_rne(a0[j].x); lo.y = bf16_rne(a0[j].y);
            lo.z = bf16_rne(a0[j].z); lo.w = bf16_rne(a0[j].w);
            hi.x = bf16_rne(a1[j].x); hi.y = bf16_rne(a1[j].y);
            hi.z = bf16_rne(a1[j].z); hi.w = bf16_rne(a1[j].w);
            ushort4* dst = (ushort4*)&As[ldsOffA[j]];
            dst[0] = lo;
            dst[1] = hi;
        }

        __syncthreads();   // B gloads (vmcnt) + A writes (lgkmcnt) drained

        #pragma unroll
        for (int ks = 0; ks < 2; ++ks) {
            const unsigned slot8 = (slotB ^ (unsigned)(ks * 4)) * 8u;
            bf16x8 af[4], bfr[4];
            #pragma unroll
            for (int i = 0; i < 4; ++i)
                af[i] = *(const bf16x8*)(&As[aRowOff + i * 1024 + slot8]);
            #pragma unroll
            for (int j = 0; j < 4; ++j)
                bfr[j] = *(const bf16x8*)(&Bs[bRowOff + j * 1024 + slot8]);
            #pragma unroll
            for (int i = 0; i < 4; ++i)
                #pragma unroll
                for (int j = 0; j < 4; ++j)
                    acc[i][j] = __builtin_amdgcn_mfma_f32_16x16x32_bf16(
                        af[i], bfr[j], acc[i][j], 0, 0, 0);
        }
    }

    // ---- zero-row flags -> per-patient scaler ----
    #pragma unroll
    for (int j = 0; j < 4; ++j)
        atomicOr(&rowOr[j * 32 + sr], orAcc[j]);
    __syncthreads();
    if (t < 32) {
        const int z = (rowOr[4 * t + 0] == 0u) + (rowOr[4 * t + 1] == 0u)
                    + (rowOr[4 * t + 2] == 0u) + (rowOr[4 * t + 3] == 0u);
        scalerS[t] = (z > 0) ? (float)(z + 1) : 1.0f;
    }
    __syncthreads();

    // ---- epilogue: softmax over modalities, weighted sum, scale, nt-store ----
    #pragma unroll
    for (int i = 0; i < 4; ++i) {
        const int bl = wm * 16 + i * 4 + quad;
        const int b  = rowb * 32 + bl;
        const float scal = scalerS[bl];
        #pragma unroll
        for (int j = 0; j < 4; ++j) {
            const int k = col0 + wn * 64 + j * 16 + ln15;
            const size_t off = (size_t)b * M_LEN + k;
            const float x0 = mod0[off], x1 = mod1[off];
            const float x2 = mod2[off], x3 = mod3[off];
            const f32x4 s = acc[i][j];
            const float mx = fmaxf(fmaxf(s.x, s.y), fmaxf(s.z, s.w));
            const float e0 = __expf(s.x - mx);
            const float e1 = __expf(s.y - mx);
            const float e2 = __expf(s.z - mx);
            const float e3 = __expf(s.w - mx);
            const float num = e0 * x0 + e1 * x1 + e2 * x2 + e3 * x3;
            const float v = num * scal / (e0 + e1 + e2 + e3);
            __builtin_nontemporal_store(v, &out[off]);
        }
    }
}

// ---------------- fallback: single fused kernel (used if ws too small) ----------
__global__ __launch_bounds__(THREADS) void fused_modal_attn(
    const float* __restrict__ mod0, const float* __restrict__ mod1,
    const float* __restrict__ mod2, const float* __restrict__ mod3,
    const float* __restrict__ W, float* __restrict__ out)
{
    __shared__ __align__(16) unsigned short As[BM * BK];
    __shared__ __align__(16) unsigned short Bs[BN * BK];
    __shared__ unsigned rowOr[BM];
    __shared__ float scalerS[BM / 4];

    const int t    = threadIdx.x;
    const int lane = t & 63;
    const int wave = t >> 6;
    const int quad = lane >> 4;
    const int ln15 = lane & 15;
    const int wm   = wave >> 1;
    const int wn   = wave & 1;

    const int colb = blockIdx.x;
    const int rowb = blockIdx.y;
    const int row0 = rowb * BM;
    const int col0 = colb * BN;

    if (t < BM) rowOr[t] = 0u;

    const int sr  = t >> 3;
    const int scl = t & 7;

    const float* ap[4];
    const float* bp[4];
    unsigned ldsOff[4];
    unsigned orAcc[4] = {0u, 0u, 0u, 0u};
    #pragma unroll
    for (int j = 0; j < 4; ++j) {
        const int r  = j * 32 + sr;
        const int gr = row0 + r;
        const int b  = gr >> 2;
        const int m  = gr & 3;
        const float* mp = (m == 0) ? mod0 : (m == 1) ? mod1 : (m == 2) ? mod2 : mod3;
        ap[j] = mp + (size_t)b * M_LEN + scl * 8;
        bp[j] = W + (size_t)(col0 + r) * M_LEN + scl * 8;
        ldsOff[j] = (unsigned)(r * 64 + ((scl ^ (r & 7)) * 8));
    }

    f32x4 acc[4][4];
    #pragma unroll
    for (int i = 0; i < 4; ++i)
        #pragma unroll
        for (int j = 0; j < 4; ++j)
            acc[i][j] = (f32x4){0.f, 0.f, 0.f, 0.f};

    const unsigned slotB   = (unsigned)(quad ^ (ln15 & 7));
    const unsigned aRowOff = (unsigned)((wm * 64 + ln15) * 64);
    const unsigned bRowOff = (unsigned)((wn * 64 + ln15) * 64);

    for (int it = 0; it < 16; ++it) {
        __syncthreads();
        #pragma unroll
        for (int j = 0; j < 4; ++j) {
            const float4* pa = (const float4*)ap[j];
            const float4* pb = (const float4*)bp[j];
            float4 a0 = pa[0], a1 = pa[1];
            float4 b0 = pb[0], b1 = pb[1];
            ap[j] += BK; bp[j] += BK;

            unsigned pA0 = pack2(a0.x, a0.y), pA1 = pack2(a0.z, a0.w);
            unsigned pA2 = pack2(a1.x, a1.y), pA3 = pack2(a1.z, a1.w);
            orAcc[j] |= (pA0 | pA1) | (pA2 | pA3);
            *(uint4*)(&As[ldsOff[j]]) = make_uint4(pA0, pA1, pA2, pA3);

            unsigned pB0 = pack2(b0.x, b0.y), pB1 = pack2(b0.z, b0.w);
            unsigned pB2 = pack2(b1.x, b1.y), pB3 = pack2(b1.z, b1.w);
            *(uint4*)(&Bs[ldsOff[j]]) = make_uint4(pB0, pB1, pB2, pB3);
        }
        __syncthreads();
        #pragma unroll
        for (int ks = 0; ks < 2; ++ks) {
            const unsigned slot8 = (slotB ^ (unsigned)(ks * 4)) * 8u;
            bf16x8 af[4], bfr[4];
            #pragma unroll
            for (int i = 0; i < 4; ++i)
                af[i] = *(const bf16x8*)(&As[aRowOff + i * 1024 + slot8]);
            #pragma unroll
            for (int j = 0; j < 4; ++j)
                bfr[j] = *(const bf16x8*)(&Bs[bRowOff + j * 1024 + slot8]);
            #pragma unroll
            for (int i = 0; i < 4; ++i)
                #pragma unroll
                for (int j = 0; j < 4; ++j)
                    acc[i][j] = __builtin_amdgcn_mfma_f32_16x16x32_bf16(
                        af[i], bfr[j], acc[i][j], 0, 0, 0);
        }
    }

    #pragma unroll
    for (int j = 0; j < 4; ++j)
        atomicOr(&rowOr[j * 32 + sr], orAcc[j]);
    __syncthreads();
    if (t < 32) {
        const int z = (rowOr[4 * t + 0] == 0u) + (rowOr[4 * t + 1] == 0u)
                    + (rowOr[4 * t + 2] == 0u) + (rowOr[4 * t + 3] == 0u);
        scalerS[t] = (z > 0) ? (float)(z + 1) : 1.0f;
    }
    __syncthreads();

    #pragma unroll
    for (int i = 0; i < 4; ++i) {
        const int bl = wm * 16 + i * 4 + quad;
        const int b  = rowb * 32 + bl;
        const float scal = scalerS[bl];
        #pragma unroll
        for (int j = 0; j < 4; ++j) {
            const int k = col0 + wn * 64 + j * 16 + ln15;
            const size_t off = (size_t)b * M_LEN + k;
            const float x0 = mod0[off], x1 = mod1[off];
            const float x2 = mod2[off], x3 = mod3[off];
            const f32x4 s = acc[i][j];
            const float mx = fmaxf(fmaxf(s.x, s.y), fmaxf(s.z, s.w));
            const float e0 = __expf(s.x - mx);
            const float e1 = __expf(s.y - mx);
            const float e2 = __expf(s.z - mx);
            const float e3 = __expf(s.w - mx);
            const float num = e0 * x0 + e1 * x1 + e2 * x2 + e3 * x3;
            out[off] = num * scal / (e0 + e1 + e2 + e3);
        }
    }
}

// ---------------- launch ----------------
extern "C" void kernel_launch(void* const* d_in, const int* in_sizes, int n_in,
                              void* d_out, int out_size, void* d_ws, size_t ws_size,
                              hipStream_t stream) {
    const float* mod0 = (const float*)d_in[0];
    const float* mod1 = (const float*)d_in[1];
    const float* mod2 = (const float*)d_in[2];
    const float* mod3 = (const float*)d_in[3];
    const float* W    = (const float*)d_in[4];
    float* out = (float*)d_out;

    // workspace: W bf16 only (2 MiB)
    const size_t wbBytes = (size_t)M_LEN * M_LEN * sizeof(ushort_t);

    if (ws_size >= wbBytes) {
        ushort_t* Wb = (ushort_t*)d_ws;
        convert_w<<<dim3(M_LEN / 4), dim3(THREADS), 0, stream>>>(W, Wb);
        // 1-D grid: T1 XCD swizzle happens inside the kernel
        gemm_fused2<<<dim3((M_LEN / BN) * ((4 * BATCH) / BM)), dim3(THREADS), 0, stream>>>(
            mod0, mod1, mod2, mod3, Wb, out);
    } else {
        dim3 grid(M_LEN / BN, (4 * BATCH) / BM);
        fused_modal_attn<<<grid, dim3(THREADS), 0, stream>>>(
            mod0, mod1, mod2, mod3, W, out);
    }
}

// Round 3
// 384.191 us; speedup vs baseline: 1.2781x; 1.2781x over previous
//
#include <hip/hip_runtime.h>
#include <hip/hip_bf16.h>

#define M_LEN 1024
#define BATCH 16384

// convert / fallback kernel tiling
#define BM 128
#define BN 128
#define BK 64
#define THREADS 256

// main gemm tiling (256^2, 8 waves)
#define BM2 256
#define BN2 256
#define GTHREADS 512

typedef __attribute__((ext_vector_type(8))) short bf16x8;
typedef __attribute__((ext_vector_type(4))) float f32x4;
typedef unsigned short ushort_t;

// ---------------- helpers ----------------

// fp32 -> bf16 RNE
__device__ __forceinline__ ushort_t bf16_rne(float f) {
    unsigned u = __float_as_uint(f);
    unsigned r = u + 0x7FFFu + ((u >> 16) & 1u);
    return (ushort_t)(r >> 16);
}

__device__ __forceinline__ float bf16_to_f(ushort_t u) {
    return __uint_as_float(((unsigned)u) << 16);
}

// pack two fp32 -> two bf16 (RTZ) in one v_perm_b32 (fallback kernel only)
__device__ __forceinline__ unsigned pack2(float lo, float hi) {
    return __builtin_amdgcn_perm(__float_as_uint(hi), __float_as_uint(lo), 0x07060302u);
}

// async global->LDS, 16B per lane. LDS dest is wave-uniform base + lane*16.
__device__ __forceinline__ void gload_lds16(const void* g, void* l) {
    __builtin_amdgcn_global_load_lds(
        (const __attribute__((address_space(1))) unsigned int*)g,
        (__attribute__((address_space(3))) unsigned int*)l,
        16, 0, 0);
}

// non-temporal 16B load
__device__ __forceinline__ float4 ntload4(const float4* p) {
    f32x4 v = __builtin_nontemporal_load((const f32x4*)p);
    return make_float4(v.x, v.y, v.z, v.w);
}

// ---------------- pass 1: fp32 -> bf16 conversion + zero-row flags ----------------
// ~85 us, at its ~83 us streaming roofline (back-solved R0-R2) — unchanged.
__global__ __launch_bounds__(THREADS) void convert_pass(
    const float* __restrict__ mod0, const float* __restrict__ mod1,
    const float* __restrict__ mod2, const float* __restrict__ mod3,
    const float* __restrict__ W,
    ushort_t* __restrict__ Ab, ushort_t* __restrict__ Wb, int* __restrict__ zf)
{
    const int blk  = blockIdx.x;
    const int wave = threadIdx.x >> 6;
    const int lane = threadIdx.x & 63;

    if (blk < BATCH) {
        const int b = blk, m = wave;
        const float* mp = (m == 0) ? mod0 : (m == 1) ? mod1 : (m == 2) ? mod2 : mod3;
        const float4* row = (const float4*)(mp + (size_t)b * M_LEN);
        ushort_t* dst = Ab + ((size_t)b * 4 + m) * M_LEN;
        unsigned orr = 0u;
        #pragma unroll
        for (int j = 0; j < 4; ++j) {
            float4 v = ntload4(&row[j * 64 + lane]);
            orr |= (__float_as_uint(v.x) | __float_as_uint(v.y) |
                    __float_as_uint(v.z) | __float_as_uint(v.w)) << 1;  // drop signs
            ushort4 o;
            o.x = bf16_rne(v.x); o.y = bf16_rne(v.y);
            o.z = bf16_rne(v.z); o.w = bf16_rne(v.w);
            ((ushort4*)dst)[j * 64 + lane] = o;
        }
        const int nz = __any(orr != 0u);
        if (lane == 0) zf[b * 4 + m] = nz ? 0 : 1;
    } else {
        const int r = (blk - BATCH) * 4 + wave;
        const float4* row = (const float4*)(W + (size_t)r * M_LEN);
        ushort_t* dst = Wb + (size_t)r * M_LEN;
        #pragma unroll
        for (int j = 0; j < 4; ++j) {
            float4 v = row[j * 64 + lane];
            ushort4 o;
            o.x = bf16_rne(v.x); o.y = bf16_rne(v.y);
            o.z = bf16_rne(v.z); o.w = bf16_rne(v.w);
            ((ushort4*)dst)[j * 64 + lane] = o;
        }
    }
}

// ---------------- pass 2: 256^2 bf16 GEMM, 2-deep counted-vmcnt pipeline ----------
// Structure (round-3): 8 waves (2M x 4N), per-wave 128x64 output, BK=64,
// double-buffered LDS (As0/Bs0, As1/Bs1 = 128 KB), 1 block/CU.
// Main loop NEVER drains vmcnt to 0: vmcnt(8) waits only for the K-tile staged
// one full tile ago (8 gload_lds16/thread/tile), so its ~L2 latency hides under
// 64 MFMA/wave of the current tile. Race story:
//  - STAGE into buf[c] is issued only after the s_barrier that every wave
//    reaches only after its ds_reads of buf[c] retired (compiler lgkmcnt
//    precedes each consuming MFMA).
//  - Reads of buf[c^1] after the next barrier are covered by each wave's own
//    vmcnt(8) before that barrier (own 8 loads of that tile retired).
// Static buffer names via unroll-by-2 (rule #20); raw s_barrier + asm waitcnt
// with "memory" clobbers only (no compiler vmcnt(0) drain).
__global__ __launch_bounds__(GTHREADS, 2) void gemm_fused3(
    const ushort_t* __restrict__ Ab, const ushort_t* __restrict__ Wb,
    const int* __restrict__ zf, float* __restrict__ out)
{
    __shared__ __align__(16) ushort_t As0[BM2 * BK];   // 32 KB
    __shared__ __align__(16) ushort_t Bs0[BN2 * BK];   // 32 KB
    __shared__ __align__(16) ushort_t As1[BM2 * BK];   // 32 KB
    __shared__ __align__(16) ushort_t Bs1[BN2 * BK];   // 32 KB
    __shared__ float scalerS[BM2 / 4];                 // 64 patients

    const int t    = threadIdx.x;
    const int lane = t & 63;
    const int wave = t >> 6;          // 0..7
    const int quad = lane >> 4;
    const int ln15 = lane & 15;
    const int wm   = wave >> 2;       // 0..1 : rows wm*128..+128
    const int wn   = wave & 3;        // 0..3 : cols wn*64..+64

    // T1: XCD-aware bijective remap. 1024 blocks, 8 XCDs, 1024 % 8 == 0.
    const int bid  = blockIdx.x;
    const int wid  = (bid & 7) * 128 + (bid >> 3);
    const int colb = wid & 3;          // 4 col panels of 256
    const int rowb = wid >> 2;         // 256 row panels of 256
    const int row0 = rowb * BM2;
    const int col0 = colb * BN2;

    if (t < 64) {
        const int4 f = ((const int4*)zf)[rowb * 64 + t];
        const int z = f.x + f.y + f.z + f.w;
        scalerS[t] = (z > 0) ? (float)(z + 1) : 1.0f;
    }

    // staging: wave w, round q covers rows w*32 + q*8 + (lane>>3);
    // physical LDS slot = lane&7 (linear dest), global chunk = (lane&7)^(row&7)
    const int rloc = (lane >> 3);
    const int c8   = (lane & 7) ^ rloc;   // row&7 == rloc here (rows are 8-aligned)
    const ushort_t* aP[4];
    const ushort_t* bP[4];
    unsigned dstOff[4];
    #pragma unroll
    for (int q = 0; q < 4; ++q) {
        const int r = wave * 32 + q * 8 + rloc;
        aP[q] = Ab + (size_t)(row0 + r) * M_LEN + c8 * 8;
        bP[q] = Wb + (size_t)(col0 + r) * M_LEN + c8 * 8;
        dstOff[q] = (unsigned)((wave * 32 + q * 8) * 64);   // ushort units
    }

    // stage one K-tile (4 A rounds + 4 B rounds = 8 gload_lds16), advance ptrs
    #define STAGE(AD, BD)                                                   \
        do {                                                                \
            _Pragma("unroll")                                               \
            for (int q = 0; q < 4; ++q) {                                   \
                gload_lds16(aP[q], (AD) + dstOff[q]);                       \
                aP[q] += BK;                                                \
            }                                                               \
            _Pragma("unroll")                                               \
            for (int q = 0; q < 4; ++q) {                                   \
                gload_lds16(bP[q], (BD) + dstOff[q]);                       \
                bP[q] += BK;                                                \
            }                                                               \
        } while (0)

    f32x4 acc[8][4];
    #pragma unroll
    for (int i = 0; i < 8; ++i)
        #pragma unroll
        for (int j = 0; j < 4; ++j)
            acc[i][j] = (f32x4){0.f, 0.f, 0.f, 0.f};

    const unsigned slotB   = (unsigned)(quad ^ (ln15 & 7));
    const unsigned aRowOff = (unsigned)((wm * 128 + ln15) * 64);
    const unsigned bRowOff = (unsigned)((wn * 64 + ln15) * 64);

    auto compute = [&](const ushort_t* As_, const ushort_t* Bs_) {
        #pragma unroll
        for (int ks = 0; ks < 2; ++ks) {
            const unsigned slot8 = (slotB ^ (unsigned)(ks * 4)) * 8u;
            bf16x8 af[8], bfr[4];
            #pragma unroll
            for (int i = 0; i < 8; ++i)
                af[i] = *(const bf16x8*)(&As_[aRowOff + i * 1024 + slot8]);
            #pragma unroll
            for (int j = 0; j < 4; ++j)
                bfr[j] = *(const bf16x8*)(&Bs_[bRowOff + j * 1024 + slot8]);
            #pragma unroll
            for (int i = 0; i < 8; ++i)
                #pragma unroll
                for (int j = 0; j < 4; ++j)
                    acc[i][j] = __builtin_amdgcn_mfma_f32_16x16x32_bf16(
                        af[i], bfr[j], acc[i][j], 0, 0, 0);
        }
    };

    // prologue: stage K0 -> buf0, K1 -> buf1; wait K0 (8 newest = K1 in flight)
    STAGE(As0, Bs0);
    STAGE(As1, Bs1);
    asm volatile("s_waitcnt vmcnt(8) lgkmcnt(0)" ::: "memory");
    __builtin_amdgcn_s_barrier();

    // steady state: 7 iterations x 2 K-tiles (K0..K13), staging K2..K15
    #pragma unroll 1
    for (int t2 = 0; t2 < 7; ++t2) {
        compute(As0, Bs0);                 // K-tile 2*t2
        __builtin_amdgcn_s_barrier();      // all waves done reading buf0
        STAGE(As0, Bs0);                   // K-tile 2*t2+2 -> buf0
        asm volatile("s_waitcnt vmcnt(8)" ::: "memory");   // 2*t2+1 landed
        __builtin_amdgcn_s_barrier();

        compute(As1, Bs1);                 // K-tile 2*t2+1
        __builtin_amdgcn_s_barrier();      // all waves done reading buf1
        STAGE(As1, Bs1);                   // K-tile 2*t2+3 -> buf1
        asm volatile("s_waitcnt vmcnt(8)" ::: "memory");   // 2*t2+2 landed
        __builtin_amdgcn_s_barrier();
    }
    // tail: K14 (landed: last loop wait left only K15's 8 outstanding)
    compute(As0, Bs0);
    asm volatile("s_waitcnt vmcnt(0)" ::: "memory");       // K15 landed
    __builtin_amdgcn_s_barrier();
    compute(As1, Bs1);

    // ---- epilogue: modality softmax + weighted sum + scaler, nt-store ----
    // C/D 16x16 layout: col = ln15, row = quad*4 + reg; A rows are (4b+m)
    // interleaved -> reg == modality, patient-in-frag == quad.
    #pragma unroll
    for (int i = 0; i < 8; ++i) {
        const int bl = wm * 32 + i * 4 + quad;      // patient within block
        const int b  = rowb * 64 + bl;
        const float scal = scalerS[bl];
        const ushort_t* xr = Ab + (size_t)b * 4 * M_LEN;   // row 4b (modality 0)
        #pragma unroll
        for (int j = 0; j < 4; ++j) {
            const int k = col0 + wn * 64 + j * 16 + ln15;
            const float x0 = bf16_to_f(xr[k]);
            const float x1 = bf16_to_f(xr[M_LEN + k]);
            const float x2 = bf16_to_f(xr[2 * M_LEN + k]);
            const float x3 = bf16_to_f(xr[3 * M_LEN + k]);
            const f32x4 s = acc[i][j];
            const float mx = fmaxf(fmaxf(s.x, s.y), fmaxf(s.z, s.w));
            const float e0 = __expf(s.x - mx);
            const float e1 = __expf(s.y - mx);
            const float e2 = __expf(s.z - mx);
            const float e3 = __expf(s.w - mx);
            const float num = e0 * x0 + e1 * x1 + e2 * x2 + e3 * x3;
            const float v = num * scal / (e0 + e1 + e2 + e3);
            __builtin_nontemporal_store(v, &out[(size_t)b * M_LEN + k]);
        }
    }
    #undef STAGE
}

// ---------------- fallback: single fused kernel (used if ws too small) ----------
__global__ __launch_bounds__(THREADS) void fused_modal_attn(
    const float* __restrict__ mod0, const float* __restrict__ mod1,
    const float* __restrict__ mod2, const float* __restrict__ mod3,
    const float* __restrict__ W, float* __restrict__ out)
{
    __shared__ __align__(16) unsigned short As[BM * BK];
    __shared__ __align__(16) unsigned short Bs[BN * BK];
    __shared__ unsigned rowOr[BM];
    __shared__ float scalerS[BM / 4];

    const int t    = threadIdx.x;
    const int lane = t & 63;
    const int wave = t >> 6;
    const int quad = lane >> 4;
    const int ln15 = lane & 15;
    const int wm   = wave >> 1;
    const int wn   = wave & 1;

    const int colb = blockIdx.x;
    const int rowb = blockIdx.y;
    const int row0 = rowb * BM;
    const int col0 = colb * BN;

    if (t < BM) rowOr[t] = 0u;

    const int sr  = t >> 3;
    const int scl = t & 7;

    const float* ap[4];
    const float* bp[4];
    unsigned ldsOff[4];
    unsigned orAcc[4] = {0u, 0u, 0u, 0u};
    #pragma unroll
    for (int j = 0; j < 4; ++j) {
        const int r  = j * 32 + sr;
        const int gr = row0 + r;
        const int b  = gr >> 2;
        const int m  = gr & 3;
        const float* mp = (m == 0) ? mod0 : (m == 1) ? mod1 : (m == 2) ? mod2 : mod3;
        ap[j] = mp + (size_t)b * M_LEN + scl * 8;
        bp[j] = W + (size_t)(col0 + r) * M_LEN + scl * 8;
        ldsOff[j] = (unsigned)(r * 64 + ((scl ^ (r & 7)) * 8));
    }

    f32x4 acc[4][4];
    #pragma unroll
    for (int i = 0; i < 4; ++i)
        #pragma unroll
        for (int j = 0; j < 4; ++j)
            acc[i][j] = (f32x4){0.f, 0.f, 0.f, 0.f};

    const unsigned slotB   = (unsigned)(quad ^ (ln15 & 7));
    const unsigned aRowOff = (unsigned)((wm * 64 + ln15) * 64);
    const unsigned bRowOff = (unsigned)((wn * 64 + ln15) * 64);

    for (int it = 0; it < 16; ++it) {
        __syncthreads();
        #pragma unroll
        for (int j = 0; j < 4; ++j) {
            const float4* pa = (const float4*)ap[j];
            const float4* pb = (const float4*)bp[j];
            float4 a0 = pa[0], a1 = pa[1];
            float4 b0 = pb[0], b1 = pb[1];
            ap[j] += BK; bp[j] += BK;

            unsigned pA0 = pack2(a0.x, a0.y), pA1 = pack2(a0.z, a0.w);
            unsigned pA2 = pack2(a1.x, a1.y), pA3 = pack2(a1.z, a1.w);
            orAcc[j] |= (pA0 | pA1) | (pA2 | pA3);
            *(uint4*)(&As[ldsOff[j]]) = make_uint4(pA0, pA1, pA2, pA3);

            unsigned pB0 = pack2(b0.x, b0.y), pB1 = pack2(b0.z, b0.w);
            unsigned pB2 = pack2(b1.x, b1.y), pB3 = pack2(b1.z, b1.w);
            *(uint4*)(&Bs[ldsOff[j]]) = make_uint4(pB0, pB1, pB2, pB3);
        }
        __syncthreads();
        #pragma unroll
        for (int ks = 0; ks < 2; ++ks) {
            const unsigned slot8 = (slotB ^ (unsigned)(ks * 4)) * 8u;
            bf16x8 af[4], bfr[4];
            #pragma unroll
            for (int i = 0; i < 4; ++i)
                af[i] = *(const bf16x8*)(&As[aRowOff + i * 1024 + slot8]);
            #pragma unroll
            for (int j = 0; j < 4; ++j)
                bfr[j] = *(const bf16x8*)(&Bs[bRowOff + j * 1024 + slot8]);
            #pragma unroll
            for (int i = 0; i < 4; ++i)
                #pragma unroll
                for (int j = 0; j < 4; ++j)
                    acc[i][j] = __builtin_amdgcn_mfma_f32_16x16x32_bf16(
                        af[i], bfr[j], acc[i][j], 0, 0, 0);
        }
    }

    #pragma unroll
    for (int j = 0; j < 4; ++j)
        atomicOr(&rowOr[j * 32 + sr], orAcc[j]);
    __syncthreads();
    if (t < 32) {
        const int z = (rowOr[4 * t + 0] == 0u) + (rowOr[4 * t + 1] == 0u)
                    + (rowOr[4 * t + 2] == 0u) + (rowOr[4 * t + 3] == 0u);
        scalerS[t] = (z > 0) ? (float)(z + 1) : 1.0f;
    }
    __syncthreads();

    #pragma unroll
    for (int i = 0; i < 4; ++i) {
        const int bl = wm * 16 + i * 4 + quad;
        const int b  = rowb * 32 + bl;
        const float scal = scalerS[bl];
        #pragma unroll
        for (int j = 0; j < 4; ++j) {
            const int k = col0 + wn * 64 + j * 16 + ln15;
            const size_t off = (size_t)b * M_LEN + k;
            const float x0 = mod0[off], x1 = mod1[off];
            const float x2 = mod2[off], x3 = mod3[off];
            const f32x4 s = acc[i][j];
            const float mx = fmaxf(fmaxf(s.x, s.y), fmaxf(s.z, s.w));
            const float e0 = __expf(s.x - mx);
            const float e1 = __expf(s.y - mx);
            const float e2 = __expf(s.z - mx);
            const float e3 = __expf(s.w - mx);
            const float num = e0 * x0 + e1 * x1 + e2 * x2 + e3 * x3;
            out[off] = num * scal / (e0 + e1 + e2 + e3);
        }
    }
}

// ---------------- launch ----------------
extern "C" void kernel_launch(void* const* d_in, const int* in_sizes, int n_in,
                              void* d_out, int out_size, void* d_ws, size_t ws_size,
                              hipStream_t stream) {
    const float* mod0 = (const float*)d_in[0];
    const float* mod1 = (const float*)d_in[1];
    const float* mod2 = (const float*)d_in[2];
    const float* mod3 = (const float*)d_in[3];
    const float* W    = (const float*)d_in[4];
    float* out = (float*)d_out;

    // workspace layout: A' bf16 (128 MiB) | W bf16 (2 MiB) | zf int[65536] (256 KiB)
    const size_t abBytes = (size_t)4 * BATCH * M_LEN * sizeof(ushort_t);
    const size_t wbBytes = (size_t)M_LEN * M_LEN * sizeof(ushort_t);
    const size_t zfBytes = (size_t)4 * BATCH * sizeof(int);
    const size_t need = abBytes + wbBytes + zfBytes;

    if (ws_size >= need) {
        ushort_t* Ab = (ushort_t*)d_ws;
        ushort_t* Wb = (ushort_t*)((char*)d_ws + abBytes);
        int*      zfp = (int*)((char*)d_ws + abBytes + wbBytes);

        convert_pass<<<dim3(BATCH + M_LEN / 4), dim3(THREADS), 0, stream>>>(
            mod0, mod1, mod2, mod3, W, Ab, Wb, zfp);

        // 1024 blocks (4 colb x 256 rowb), T1 swizzle inside the kernel
        gemm_fused3<<<dim3((M_LEN / BN2) * ((4 * BATCH) / BM2)), dim3(GTHREADS), 0, stream>>>(
            Ab, Wb, zfp, out);
    } else {
        dim3 grid(M_LEN / BN, (4 * BATCH) / BM);
        fused_modal_attn<<<grid, dim3(THREADS), 0, stream>>>(
            mod0, mod1, mod2, mod3, W, out);
    }
}